// Round 4
// baseline (194.363 us; speedup 1.0000x reference)
//
#include <hip/hip_runtime.h>

#define BETA   0.1f
#define MARGIN 0.1f
#define EPSF   1e-6f
#define KNEG   4
#define PPB    8            // pairs per block
#define NROWS  (PPB * 6)    // 48 rows x 1KB = 48KB LDS
#define PI_2   1.57079632679489662f

__device__ __forceinline__ float dot4(float4 a, float4 b) {
    return a.x*b.x + a.y*b.y + a.z*b.z + a.w*b.w;
}

// reduce across a 32-lane half-wave (xor offsets stay within the half)
__device__ __forceinline__ float hsum32(float v) {
    #pragma unroll
    for (int off = 16; off >= 1; off >>= 1)
        v += __shfl_xor(v, off, 64);
    return v;
}

__device__ __forceinline__ float wave_sum(float v) {
    #pragma unroll
    for (int off = 32; off >= 1; off >>= 1)
        v += __shfl_xor(v, off, 64);
    return v;
}

// 8 pairs/block. Rows staged to LDS via async DMA (zero data-VGPRs -> all 48
// row loads in flight at once). Wave w owns pairs {2w,2w+1}: DMAs their 12
// rows, computes dots with half-wave per pair, then evaluates ALL of the
// wave's 12 transcendentals with ONE lane-scattered acosf.
__global__ __launch_bounds__(256) void cone_main(
    const float* __restrict__ proto,
    const int*   __restrict__ pairs,
    const int*   __restrict__ negc,
    float*       __restrict__ part,   // [2*gridDim]
    int P)
{
    __shared__ float rows[NROWS * 256];   // 48KB
    __shared__ float sp[4], sn[4];

    const int lane = threadIdx.x & 63;
    const int w    = threadIdx.x >> 6;
    const int blk  = blockIdx.x;

    // ---- gather the block's 48 indices, one per lane (lanes 0..47) ----
    int myidx = 0;
    {
        int o1 = blk * (2 * PPB) + lane;              // pairs: 16 ints
        int o2 = blk * (4 * PPB) + (lane - 16);       // negc: 32 ints
        if (lane < 16)      myidx = pairs[min(o1, 2 * P - 1)];
        else if (lane < 48) myidx = negc[min(o2, 4 * P - 1)];
    }

    // ---- async DMA: wave w stages rows 12w .. 12w+11 ----
    #pragma unroll
    for (int rr = 0; rr < 12; ++rr) {
        const int r = w * 12 + rr;
        const int q = r / 6, t = r % 6;               // pair-local, role
        const int src = (t < 2) ? (2 * q + t) : (16 + 4 * q + (t - 2));
        const int idx = __shfl(myidx, src, 64);
        const float* gp = proto + (size_t)idx * 256 + lane * 4;  // lane*16B
        __builtin_amdgcn_global_load_lds(
            (const __attribute__((address_space(1))) void*)gp,
            (__attribute__((address_space(3))) void*)&rows[r * 256],
            16, 0, 0);
    }
    __syncthreads();   // drains vmcnt -> all rows resident

    // ---- compute: half-wave per pair ----
    const int q  = lane >> 5;            // which pair within the wave
    const int hl = lane & 31;
    const int pl = w * 2 + q;            // pair-local id 0..7
    const float4* r4 = (const float4*)rows;

    const int pbase = (pl * 6) * 64;
    float4 p0 = r4[pbase + hl];
    float4 p1 = r4[pbase + 32 + hl];
    float p2 = hsum32(dot4(p0, p0) + dot4(p1, p1));
    float norm_p = sqrtf(p2);
    float asin_arg = fminf(fmaxf(BETA / (norm_p + EPSF), 0.f), 1.f - EPSF);

    // lane-scatter targets: lane l<12 collects value tj of pair tq
    const int tq = (lane < 6) ? 0 : 1;
    const int tj = lane - 6 * tq;        // only meaningful for lane<12
    float my_t = 0.f;

    #pragma unroll
    for (int j = 1; j <= 5; ++j) {
        const int cb = (pl * 6 + j) * 64;
        float4 c0 = r4[cb + hl];
        float4 c1 = r4[cb + 32 + hl];
        float cc = dot4(c0, c0) + dot4(c1, c1);
        float d0x = c0.x - p0.x, d0y = c0.y - p0.y, d0z = c0.z - p0.z, d0w = c0.w - p0.w;
        float d1x = c1.x - p1.x, d1y = c1.y - p1.y, d1z = c1.z - p1.z, d1w = c1.w - p1.w;
        float dd = d0x*d0x + d0y*d0y + d0z*d0z + d0w*d0w
                 + d1x*d1x + d1y*d1y + d1z*d1z + d1w*d1w;
        cc = hsum32(cc);
        dd = hsum32(dd);
        // reference numerics: num = |c|^2 - |p|^2 - |c-p|^2
        float num    = cc - p2 - dd;
        float den    = 2.f * norm_p * sqrtf(dd) + EPSF;
        float ca     = fminf(fmaxf(num / den, -1.f + EPSF), 1.f - EPSF);
        // scatter: lane q*6+(j-1) keeps pair q's cosang_j
        float v0 = __shfl(ca, 0, 64);
        float v1 = __shfl(ca, 32, 64);
        my_t = (tj == j - 1) ? (tq ? v1 : v0) : my_t;
    }
    {   // slot tj==5 holds the asin argument (asin(x) = pi/2 - acos(x))
        float v0 = __shfl(asin_arg, 0, 64);
        float v1 = __shfl(asin_arg, 32, 64);
        my_t = (tj == 5) ? (tq ? v1 : v0) : my_t;
    }

    // ONE wave-wide acos evaluates all 12 transcendentals of this wave
    float ang = acosf(my_t);

    // aperture_q = pi/2 - ang(lane q*6+5)
    float a0 = __shfl(ang, 5, 64);
    float a1 = __shfl(ang, 11, 64);
    float apert = PI_2 - (tq ? a1 : a0);
    float e = fmaxf(ang - apert, 0.f);

    const int pair_g = blk * PPB + tq + 2 * w;   // global pair id for my slot
    const bool valid = (lane < 12) && (pair_g < P);
    float pos_c = (valid && tj == 0)            ? e                        : 0.f;
    float neg_c = (valid && tj >= 1 && tj <= 5 - 1) ? fmaxf(MARGIN - e, 0.f) : 0.f;

    float ps = wave_sum(pos_c);
    float ns = wave_sum(neg_c);
    if (lane == 0) { sp[w] = ps; sn[w] = ns; }
    __syncthreads();
    if (threadIdx.x == 0) {
        part[2 * blk]     = sp[0] + sp[1] + sp[2] + sp[3];
        part[2 * blk + 1] = sn[0] + sn[1] + sn[2] + sn[3];
    }
}

__global__ __launch_bounds__(1024) void cone_final(
    const float* __restrict__ part, float* __restrict__ out, int nblocks, int P)
{
    float ps = 0.f, ns = 0.f;
    for (int i = threadIdx.x; i < nblocks; i += 1024) {
        ps += part[2 * i];
        ns += part[2 * i + 1];
    }
    ps = wave_sum(ps);
    ns = wave_sum(ns);
    const int lane = threadIdx.x & 63, wid = threadIdx.x >> 6;
    __shared__ float sp[16], sn[16];
    if (lane == 0) { sp[wid] = ps; sn[wid] = ns; }
    __syncthreads();
    if (threadIdx.x == 0) {
        float tp = 0.f, tn = 0.f;
        #pragma unroll
        for (int i = 0; i < 16; ++i) { tp += sp[i]; tn += sn[i]; }
        float fP = (float)P;
        out[0] = (tp / fP + tn / (fP * (float)KNEG)) * 0.5f;
    }
}

extern "C" void kernel_launch(void* const* d_in, const int* in_sizes, int n_in,
                              void* d_out, int out_size, void* d_ws, size_t ws_size,
                              hipStream_t stream) {
    const float* proto = (const float*)d_in[0];
    const int*   pairs = (const int*)d_in[1];
    const int*   negc  = (const int*)d_in[2];
    float*       part  = (float*)d_ws;
    const int P = in_sizes[1] / 2;
    const int nblocks = (P + PPB - 1) / PPB;

    cone_main<<<nblocks, 256, 0, stream>>>(proto, pairs, negc, part, P);
    cone_final<<<1, 1024, 0, stream>>>(part, (float*)d_out, nblocks, P);
}

// Round 5
// 177.173 us; speedup vs baseline: 1.0970x; 1.0970x over previous
//
#include <hip/hip_runtime.h>

#define BETA   0.1f
#define MARGIN 0.1f
#define EPSF   1e-6f
#define KNEG   4

typedef float f2_t __attribute__((ext_vector_type(2)));

__device__ __forceinline__ float gsum16(float v) {
    #pragma unroll
    for (int off = 8; off >= 1; off >>= 1) v += __shfl_xor(v, off, 64);
    return v;
}
__device__ __forceinline__ float wave_sum(float v) {
    #pragma unroll
    for (int off = 32; off >= 1; off >>= 1) v += __shfl_xor(v, off, 64);
    return v;
}
__device__ __forceinline__ float dot4(float4 a, float4 b) {
    return a.x*b.x + a.y*b.y + a.z*b.z + a.w*b.w;
}
__device__ __forceinline__ void unpack4(unsigned int u, float* f) {
    f2_t a = __builtin_amdgcn_cvt_pk_f32_fp8(u, false);
    f[0] = a.x; f[1] = a.y;
    a = __builtin_amdgcn_cvt_pk_f32_fp8(u, true);
    f[2] = a.x; f[3] = a.y;
}

// ---- pass 1: fp32 table -> fp8 e4m3 table (RNE), 4 elems per uint ----
__global__ __launch_bounds__(256) void cvt_fp8(
    const float* __restrict__ in, unsigned int* __restrict__ out, int n4)
{
    int i = blockIdx.x * 256 + threadIdx.x;
    const int stride = gridDim.x * 256;
    const float4* in4 = (const float4*)in;
    for (; i < n4; i += stride) {
        float4 v = in4[i];
        unsigned int p = __builtin_amdgcn_cvt_pk_fp8_f32(v.x, v.y, 0u, false);
        p = __builtin_amdgcn_cvt_pk_fp8_f32(v.z, v.w, p, true);
        out[i] = p;
    }
}

// ---- pass 2: gather+energy on fp8 rows (256 B/row; 4x less fetch) ----
// R2 structure: 4 pairs/wave, 16 lanes/pair, lane holds 16 elems (one uint4).
__global__ __launch_bounds__(256) void cone_main_fp8(
    const uint4* __restrict__ tab,   // C rows x 16 uint4
    const int*   __restrict__ pairs,
    const int*   __restrict__ negc,
    float*       __restrict__ part,
    int P)
{
    const int lane = threadIdx.x & 63;
    const int wid  = threadIdx.x >> 6;
    const int sub  = lane >> 4;
    const int sl   = lane & 15;
    const int pair = (blockIdx.x * 4 + wid) * 4 + sub;

    float pos_e = 0.f, neg_e = 0.f;
    if (pair < P) {
        const int pi = pairs[2 * pair];
        int idx[5];
        idx[0] = pairs[2 * pair + 1];
        #pragma unroll
        for (int k = 0; k < KNEG; ++k) idx[1 + k] = negc[4 * pair + k];

        // All 6 row-loads issued up-front; only 24 data VGPRs total.
        uint4 pu = tab[(size_t)pi * 16 + sl];
        uint4 cu[5];
        #pragma unroll
        for (int j = 0; j < 5; ++j) cu[j] = tab[(size_t)idx[j] * 16 + sl];

        float pf[16];
        unpack4(pu.x, pf + 0);  unpack4(pu.y, pf + 4);
        unpack4(pu.z, pf + 8);  unpack4(pu.w, pf + 12);
        float pp = 0.f;
        #pragma unroll
        for (int d = 0; d < 16; ++d) pp += pf[d] * pf[d];
        float p2     = gsum16(pp);
        float norm_p = sqrtf(p2);
        float apert  = asinf(fminf(fmaxf(BETA / (norm_p + EPSF), 0.f), 1.f - EPSF));

        #pragma unroll
        for (int j = 0; j < 5; ++j) {
            float cf[16];
            unpack4(cu[j].x, cf + 0);  unpack4(cu[j].y, cf + 4);
            unpack4(cu[j].z, cf + 8);  unpack4(cu[j].w, cf + 12);
            float cc = 0.f, dd = 0.f;
            #pragma unroll
            for (int d = 0; d < 16; ++d) {
                cc += cf[d] * cf[d];
                float t = cf[d] - pf[d];
                dd += t * t;
            }
            float c2 = gsum16(cc);
            float d2 = gsum16(dd);
            // reference numerics: num = |c|^2 - |p|^2 - |c-p|^2
            float num    = c2 - p2 - d2;
            float den    = 2.f * norm_p * sqrtf(d2) + EPSF;
            float cosang = fminf(fmaxf(num / den, -1.f + EPSF), 1.f - EPSF);
            float e      = fmaxf(acosf(cosang) - apert, 0.f);
            if (j == 0) pos_e = e;
            else        neg_e += fmaxf(MARGIN - e, 0.f);
        }
    }

    __shared__ float sp[16], sn[16];
    if (sl == 0) { sp[wid * 4 + sub] = pos_e; sn[wid * 4 + sub] = neg_e; }
    __syncthreads();
    if (threadIdx.x == 0) {
        float ps = 0.f, ns = 0.f;
        #pragma unroll
        for (int i = 0; i < 16; ++i) { ps += sp[i]; ns += sn[i]; }
        part[2 * blockIdx.x]     = ps;
        part[2 * blockIdx.x + 1] = ns;
    }
}

// ---- fp32 fallback (R2 kernel) if ws can't hold the fp8 table ----
__global__ __launch_bounds__(256) void cone_main_f32(
    const float* __restrict__ proto,
    const int*   __restrict__ pairs,
    const int*   __restrict__ negc,
    float*       __restrict__ part,
    int P)
{
    const int lane = threadIdx.x & 63;
    const int wid  = threadIdx.x >> 6;
    const int sub  = lane >> 4;
    const int sl   = lane & 15;
    const int pair = (blockIdx.x * 4 + wid) * 4 + sub;

    float pos_e = 0.f, neg_e = 0.f;
    if (pair < P) {
        const int pi = pairs[2 * pair];
        int idx[5];
        idx[0] = pairs[2 * pair + 1];
        #pragma unroll
        for (int k = 0; k < KNEG; ++k) idx[1 + k] = negc[4 * pair + k];

        const float4* prow = (const float4*)(proto + (size_t)pi * 256);
        float4 pv[4];
        #pragma unroll
        for (int r = 0; r < 4; ++r) pv[r] = prow[sl + 16 * r];

        float pp = 0.f;
        #pragma unroll
        for (int r = 0; r < 4; ++r) pp += dot4(pv[r], pv[r]);
        float p2     = gsum16(pp);
        float norm_p = sqrtf(p2);
        float apert  = asinf(fminf(fmaxf(BETA / (norm_p + EPSF), 0.f), 1.f - EPSF));

        #pragma unroll
        for (int j = 0; j < 5; ++j) {
            const float4* crow = (const float4*)(proto + (size_t)idx[j] * 256);
            float cc = 0.f, dd = 0.f;
            #pragma unroll
            for (int r = 0; r < 4; ++r) {
                float4 c = crow[sl + 16 * r], p = pv[r];
                cc += dot4(c, c);
                float dx = c.x - p.x, dy = c.y - p.y, dz = c.z - p.z, dw = c.w - p.w;
                dd += dx*dx + dy*dy + dz*dz + dw*dw;
            }
            float c2 = gsum16(cc);
            float d2 = gsum16(dd);
            float num    = c2 - p2 - d2;
            float den    = 2.f * norm_p * sqrtf(d2) + EPSF;
            float cosang = fminf(fmaxf(num / den, -1.f + EPSF), 1.f - EPSF);
            float e      = fmaxf(acosf(cosang) - apert, 0.f);
            if (j == 0) pos_e = e;
            else        neg_e += fmaxf(MARGIN - e, 0.f);
        }
    }

    __shared__ float sp[16], sn[16];
    if (sl == 0) { sp[wid * 4 + sub] = pos_e; sn[wid * 4 + sub] = neg_e; }
    __syncthreads();
    if (threadIdx.x == 0) {
        float ps = 0.f, ns = 0.f;
        #pragma unroll
        for (int i = 0; i < 16; ++i) { ps += sp[i]; ns += sn[i]; }
        part[2 * blockIdx.x]     = ps;
        part[2 * blockIdx.x + 1] = ns;
    }
}

__global__ __launch_bounds__(1024) void cone_final(
    const float* __restrict__ part, float* __restrict__ out, int nblocks, int P)
{
    float ps = 0.f, ns = 0.f;
    for (int i = threadIdx.x; i < nblocks; i += 1024) {
        ps += part[2 * i];
        ns += part[2 * i + 1];
    }
    ps = wave_sum(ps);
    ns = wave_sum(ns);
    const int lane = threadIdx.x & 63, wid = threadIdx.x >> 6;
    __shared__ float sp[16], sn[16];
    if (lane == 0) { sp[wid] = ps; sn[wid] = ns; }
    __syncthreads();
    if (threadIdx.x == 0) {
        float tp = 0.f, tn = 0.f;
        #pragma unroll
        for (int i = 0; i < 16; ++i) { tp += sp[i]; tn += sn[i]; }
        float fP = (float)P;
        out[0] = (tp / fP + tn / (fP * (float)KNEG)) * 0.5f;
    }
}

extern "C" void kernel_launch(void* const* d_in, const int* in_sizes, int n_in,
                              void* d_out, int out_size, void* d_ws, size_t ws_size,
                              hipStream_t stream) {
    const float* proto = (const float*)d_in[0];
    const int*   pairs = (const int*)d_in[1];
    const int*   negc  = (const int*)d_in[2];
    const int P = in_sizes[1] / 2;
    const int nblocks = (P + 15) / 16;

    const size_t tab_bytes = (size_t)in_sizes[0];              // 1 B / element
    const size_t need = tab_bytes + (size_t)nblocks * 2 * sizeof(float);

    if (ws_size >= need) {
        unsigned int* tab  = (unsigned int*)d_ws;
        float*        part = (float*)((char*)d_ws + tab_bytes);
        const int n4 = in_sizes[0] / 4;
        cvt_fp8<<<8192, 256, 0, stream>>>(proto, tab, n4);
        cone_main_fp8<<<nblocks, 256, 0, stream>>>((const uint4*)tab, pairs, negc, part, P);
        cone_final<<<1, 1024, 0, stream>>>(part, (float*)d_out, nblocks, P);
    } else {
        float* part = (float*)d_ws;
        cone_main_f32<<<nblocks, 256, 0, stream>>>(proto, pairs, negc, part, P);
        cone_final<<<1, 1024, 0, stream>>>(part, (float*)d_out, nblocks, P);
    }
}

// Round 6
// 174.722 us; speedup vs baseline: 1.1124x; 1.0140x over previous
//
#include <hip/hip_runtime.h>

#define BETA   0.1f
#define MARGIN 0.1f
#define EPSF   1e-6f
#define KNEG   4

typedef float f2_t __attribute__((ext_vector_type(2)));

__device__ __forceinline__ float gsum16(float v) {
    #pragma unroll
    for (int off = 8; off >= 1; off >>= 1) v += __shfl_xor(v, off, 64);
    return v;
}
__device__ __forceinline__ float wave_sum(float v) {
    #pragma unroll
    for (int off = 32; off >= 1; off >>= 1) v += __shfl_xor(v, off, 64);
    return v;
}
__device__ __forceinline__ float dot4(float4 a, float4 b) {
    return a.x*b.x + a.y*b.y + a.z*b.z + a.w*b.w;
}
__device__ __forceinline__ unsigned packf4(float4 v) {
    unsigned p = __builtin_amdgcn_cvt_pk_fp8_f32(v.x, v.y, 0u, false);
    return __builtin_amdgcn_cvt_pk_fp8_f32(v.z, v.w, p, true);
}
__device__ __forceinline__ void unpack4(unsigned u, float* f) {
    f2_t a = __builtin_amdgcn_cvt_pk_f32_fp8(u, false);
    f[0] = a.x; f[1] = a.y;
    a = __builtin_amdgcn_cvt_pk_f32_fp8(u, true);
    f[2] = a.x; f[3] = a.y;
}

// ---- pass 1: fp8 table + per-row fp32 norm2 + aperture (one read of proto) ----
// 16 lanes per row; lane sl packs elements {4sl..4sl+3} of each 64-elem quarter.
__global__ __launch_bounds__(256) void cvt_fp8_norm(
    const float* __restrict__ in, uint4* __restrict__ tab,
    float* __restrict__ norm2, float* __restrict__ apert, int C)
{
    const int sl  = threadIdx.x & 15;
    const int row = (blockIdx.x * 256 + threadIdx.x) >> 4;
    if (row >= C) return;
    const float4* src = (const float4*)(in + (size_t)row * 256);
    float4 v0 = src[sl], v1 = src[sl + 16], v2 = src[sl + 32], v3 = src[sl + 48];
    uint4 u;
    u.x = packf4(v0); u.y = packf4(v1); u.z = packf4(v2); u.w = packf4(v3);
    tab[(size_t)row * 16 + sl] = u;
    float ss = gsum16(dot4(v0,v0) + dot4(v1,v1) + dot4(v2,v2) + dot4(v3,v3));
    if (sl == 0) {
        norm2[row] = ss;
        float np = sqrtf(ss);
        apert[row] = asinf(fminf(fmaxf(BETA / (np + EPSF), 0.f), 1.f - EPSF));
    }
}

// ---- pass 2: gather + energy. Dot-only inner loop (norms from fp32 tables):
//   num = c2-p2-d2 = 2(dot - p2),  d2 = c2+p2-2 dot  (guard >= 0)
// 4 pairs/wave, 16 lanes/pair, lane holds one uint4 (16 fp8 elems) per row.
__global__ __launch_bounds__(256) void cone_main_fp8(
    const uint4* __restrict__ tab,
    const float* __restrict__ norm2,
    const float* __restrict__ apert,
    const int*   __restrict__ pairs,
    const int*   __restrict__ negc,
    float*       __restrict__ part,
    int P)
{
    const int lane = threadIdx.x & 63;
    const int wid  = threadIdx.x >> 6;
    const int sub  = lane >> 4;
    const int sl   = lane & 15;
    const int pair = (blockIdx.x * 4 + wid) * 4 + sub;

    float pos_e = 0.f, neg_e = 0.f;
    if (pair < P) {
        const int pi = pairs[2 * pair];
        int idx[5];
        idx[0] = pairs[2 * pair + 1];
        #pragma unroll
        for (int k = 0; k < KNEG; ++k) idx[1 + k] = negc[4 * pair + k];

        // 6 row loads (24 data VGPRs) issued up-front.
        uint4 pu = tab[(size_t)pi * 16 + sl];
        uint4 cu[5];
        #pragma unroll
        for (int j = 0; j < 5; ++j) cu[j] = tab[(size_t)idx[j] * 16 + sl];

        // Side-table gather: lanes 0..6 of each group fetch the 7 scalars
        // (norm2[pi], apert[pi], norm2[idx[0..4]]) — tables are L2-resident.
        int tidx = (sl >= 2 && sl < 7) ? idx[sl - 2] : pi;
        const float* tbl = (sl == 1) ? apert : norm2;
        float sv = tbl[tidx];
        const int base = sub * 16;
        const float p2 = __shfl(sv, base + 0, 64);
        const float ap = __shfl(sv, base + 1, 64);
        const float np = sqrtf(p2);

        float pf[16];
        unpack4(pu.x, pf + 0);  unpack4(pu.y, pf + 4);
        unpack4(pu.z, pf + 8);  unpack4(pu.w, pf + 12);

        #pragma unroll
        for (int j = 0; j < 5; ++j) {
            float cf[16];
            unpack4(cu[j].x, cf + 0);  unpack4(cu[j].y, cf + 4);
            unpack4(cu[j].z, cf + 8);  unpack4(cu[j].w, cf + 12);
            float acc = 0.f;
            #pragma unroll
            for (int d = 0; d < 16; ++d) acc += cf[d] * pf[d];
            float dot = gsum16(acc);
            float c2  = __shfl(sv, base + 2 + j, 64);
            float num = 2.f * (dot - p2);
            float d2  = fmaxf(c2 + p2 - 2.f * dot, 0.f);
            float den = 2.f * np * sqrtf(d2) + EPSF;
            float ca  = fminf(fmaxf(num / den, -1.f + EPSF), 1.f - EPSF);
            float e   = fmaxf(acosf(ca) - ap, 0.f);
            if (j == 0) pos_e = e;
            else        neg_e += fmaxf(MARGIN - e, 0.f);
        }
    }

    __shared__ float sp[16], sn[16];
    if (sl == 0) { sp[wid * 4 + sub] = pos_e; sn[wid * 4 + sub] = neg_e; }
    __syncthreads();
    if (threadIdx.x == 0) {
        float ps = 0.f, ns = 0.f;
        #pragma unroll
        for (int i = 0; i < 16; ++i) { ps += sp[i]; ns += sn[i]; }
        part[2 * blockIdx.x]     = ps;
        part[2 * blockIdx.x + 1] = ns;
    }
}

// ---- fp32 fallback (R2 kernel) if ws can't hold the tables ----
__global__ __launch_bounds__(256) void cone_main_f32(
    const float* __restrict__ proto,
    const int*   __restrict__ pairs,
    const int*   __restrict__ negc,
    float*       __restrict__ part,
    int P)
{
    const int lane = threadIdx.x & 63;
    const int wid  = threadIdx.x >> 6;
    const int sub  = lane >> 4;
    const int sl   = lane & 15;
    const int pair = (blockIdx.x * 4 + wid) * 4 + sub;

    float pos_e = 0.f, neg_e = 0.f;
    if (pair < P) {
        const int pi = pairs[2 * pair];
        int idx[5];
        idx[0] = pairs[2 * pair + 1];
        #pragma unroll
        for (int k = 0; k < KNEG; ++k) idx[1 + k] = negc[4 * pair + k];

        const float4* prow = (const float4*)(proto + (size_t)pi * 256);
        float4 pv[4];
        #pragma unroll
        for (int r = 0; r < 4; ++r) pv[r] = prow[sl + 16 * r];

        float pp = 0.f;
        #pragma unroll
        for (int r = 0; r < 4; ++r) pp += dot4(pv[r], pv[r]);
        float p2     = gsum16(pp);
        float norm_p = sqrtf(p2);
        float apert  = asinf(fminf(fmaxf(BETA / (norm_p + EPSF), 0.f), 1.f - EPSF));

        #pragma unroll
        for (int j = 0; j < 5; ++j) {
            const float4* crow = (const float4*)(proto + (size_t)idx[j] * 256);
            float cc = 0.f, dd = 0.f;
            #pragma unroll
            for (int r = 0; r < 4; ++r) {
                float4 c = crow[sl + 16 * r], p = pv[r];
                cc += dot4(c, c);
                float dx = c.x - p.x, dy = c.y - p.y, dz = c.z - p.z, dw = c.w - p.w;
                dd += dx*dx + dy*dy + dz*dz + dw*dw;
            }
            float c2 = gsum16(cc);
            float d2 = gsum16(dd);
            float num    = c2 - p2 - d2;
            float den    = 2.f * norm_p * sqrtf(d2) + EPSF;
            float cosang = fminf(fmaxf(num / den, -1.f + EPSF), 1.f - EPSF);
            float e      = fmaxf(acosf(cosang) - apert, 0.f);
            if (j == 0) pos_e = e;
            else        neg_e += fmaxf(MARGIN - e, 0.f);
        }
    }

    __shared__ float sp[16], sn[16];
    if (sl == 0) { sp[wid * 4 + sub] = pos_e; sn[wid * 4 + sub] = neg_e; }
    __syncthreads();
    if (threadIdx.x == 0) {
        float ps = 0.f, ns = 0.f;
        #pragma unroll
        for (int i = 0; i < 16; ++i) { ps += sp[i]; ns += sn[i]; }
        part[2 * blockIdx.x]     = ps;
        part[2 * blockIdx.x + 1] = ns;
    }
}

__global__ __launch_bounds__(1024) void cone_final(
    const float* __restrict__ part, float* __restrict__ out, int nblocks, int P)
{
    float ps = 0.f, ns = 0.f;
    for (int i = threadIdx.x; i < nblocks; i += 1024) {
        ps += part[2 * i];
        ns += part[2 * i + 1];
    }
    ps = wave_sum(ps);
    ns = wave_sum(ns);
    const int lane = threadIdx.x & 63, wid = threadIdx.x >> 6;
    __shared__ float sp[16], sn[16];
    if (lane == 0) { sp[wid] = ps; sn[wid] = ns; }
    __syncthreads();
    if (threadIdx.x == 0) {
        float tp = 0.f, tn = 0.f;
        #pragma unroll
        for (int i = 0; i < 16; ++i) { tp += sp[i]; tn += sn[i]; }
        float fP = (float)P;
        out[0] = (tp / fP + tn / (fP * (float)KNEG)) * 0.5f;
    }
}

extern "C" void kernel_launch(void* const* d_in, const int* in_sizes, int n_in,
                              void* d_out, int out_size, void* d_ws, size_t ws_size,
                              hipStream_t stream) {
    const float* proto = (const float*)d_in[0];
    const int*   pairs = (const int*)d_in[1];
    const int*   negc  = (const int*)d_in[2];
    const int P = in_sizes[1] / 2;
    const int C = in_sizes[0] / 256;
    const int nblocks = (P + 15) / 16;

    const size_t tab_bytes = (size_t)in_sizes[0];              // 1 B / element
    const size_t need = tab_bytes + (size_t)C * 2 * sizeof(float)
                      + (size_t)nblocks * 2 * sizeof(float);

    if (ws_size >= need) {
        uint4* tab   = (uint4*)d_ws;
        float* norm2 = (float*)((char*)d_ws + tab_bytes);
        float* apert = norm2 + C;
        float* part  = apert + C;
        cvt_fp8_norm<<<(C + 15) / 16, 256, 0, stream>>>(proto, tab, norm2, apert, C);
        cone_main_fp8<<<nblocks, 256, 0, stream>>>(tab, norm2, apert, pairs, negc, part, P);
        cone_final<<<1, 1024, 0, stream>>>(part, (float*)d_out, nblocks, P);
    } else {
        float* part = (float*)d_ws;
        cone_main_f32<<<nblocks, 256, 0, stream>>>(proto, pairs, negc, part, P);
        cone_final<<<1, 1024, 0, stream>>>(part, (float*)d_out, nblocks, P);
    }
}